// Round 2
// baseline (140.392 us; speedup 1.0000x reference)
//
#include <hip/hip_runtime.h>

// FixedDb4DWT1D fully fused: 3-level db4 DWT + bilinear upsample + concat.
// x: (32, 16384, 64) f32 -> out: (32, 8192, 256) f32
// out channel blocks: [D1 | up2(D2) | up4(D3) | up4(A3)]
//
// One block = 16 level-3 rows = 64 output rows of one batch element.
// A1 (90 rows), A2+D2 (42 rows), D3+A3 (18 rows, aliased over dead A1) live
// entirely in LDS; only x is read and out written at HBM level.

#define NCH 64
#define NB 32
#define L0 16384
#define L1 8192
#define L2 4096
#define L3 2048

__device__ constexpr float F_LO[8] = {
    -0.010597401784997278f, 0.032883011666982945f,
    0.030841381835986965f, -0.18703481171888114f,
    -0.02798376941698385f, 0.6308807679295904f,
    0.7148465705525415f,   0.23037781330885523f};
__device__ constexpr float F_HI[8] = {
    -0.23037781330885523f, 0.7148465705525415f,
    -0.6308807679295904f,  -0.02798376941698385f,
    0.18703481171888114f,  0.030841381835986965f,
    0.032883011666982945f, -0.010597401784997278f};

__global__ __launch_bounds__(256) void k_fused(const float* __restrict__ x,
                                               float* __restrict__ out) {
  constexpr int T3 = 16;                 // level-3 rows per block
  constexpr int A1R = 4 * T3 + 26;       // 90 A1 rows, base 4*i0-13
  constexpr int A2R = 2 * T3 + 10;       // 42 A2/D2 rows, base 2*i0-5
  constexpr int D3R = T3 + 2;            // 18 D3/A3 rows, base i0-1
  __shared__ float smem[(A1R + 2 * A2R) * NCH];   // 174*64 f32 = 44.5 KB
  float* sA1 = smem;                     // [A1R][64]
  float* sA2 = smem + A1R * NCH;         // [A2R][64]
  float* sD2 = smem + (A1R + A2R) * NCH; // [A2R][64]
  float* sD3 = smem;                     // alias over dead A1: [D3R][64]
  float* sA3 = smem + D3R * NCH;         // [D3R][64]

  const int nt = L3 / T3;                // 128 tiles per batch row
  const int b = blockIdx.x / nt;
  const int i0 = (blockIdx.x % nt) * T3;
  const int c = threadIdx.x & 63;
  const int r0 = threadIdx.x >> 6;
  const float* xb = x + (size_t)b * L0 * NCH;
  float* outb = out + (size_t)b * L1 * 256;

  // ---- Stage 1: A1 rows [4i0-13, 4i0+77) from global x; D1 -> out block 0.
  const int a1base = 4 * i0 - 13;
  const int jlo = 4 * i0, jhi = 4 * i0 + 4 * T3;   // this block's out rows
  for (int r = r0; r < A1R; r += 4) {
    const int a = a1base + r;            // global level-1 row
    float lo = 0.f, hi = 0.f;
    if (a >= 0 && a < L1) {
      const int lb = 2 * a - 3;
      if (lb >= 0 && lb + 7 < L0) {
#pragma unroll
        for (int t = 0; t < 8; ++t) {
          const float v = xb[(size_t)(lb + t) * NCH + c];
          lo = fmaf(v, F_LO[t], lo);
          hi = fmaf(v, F_HI[t], hi);
        }
      } else {
#pragma unroll
        for (int t = 0; t < 8; ++t) {
          const int l = lb + t;
          const float v = (l >= 0 && l < L0) ? xb[(size_t)l * NCH + c] : 0.f;
          lo = fmaf(v, F_LO[t], lo);
          hi = fmaf(v, F_HI[t], hi);
        }
      }
    }
    sA1[r * NCH + c] = lo;               // 0 outside [0,L1) = level-2 zero-pad
    if (a >= jlo && a < jhi) outb[(size_t)a * 256 + c] = hi;  // D1 == up(D1)
  }
  __syncthreads();

  // ---- Stage 2: A2 + D2 rows [2i0-5, 2i0+37) from sA1 (taps = local 2r+t).
  const int a2base = 2 * i0 - 5;
  for (int r = r0; r < A2R; r += 4) {
    const int a = a2base + r;
    float lo = 0.f, hi = 0.f;
#pragma unroll
    for (int t = 0; t < 8; ++t) {
      const float v = sA1[(2 * r + t) * NCH + c];
      lo = fmaf(v, F_LO[t], lo);
      hi = fmaf(v, F_HI[t], hi);
    }
    sD2[r * NCH + c] = hi;
    sA2[r * NCH + c] = (a >= 0 && a < L2) ? lo : 0.f;  // level-3 zero-pad
  }
  __syncthreads();

  // ---- Stage 3: D3 + A3 rows [i0-1, i0+17) from sA2 (taps = local 2r+t).
  for (int r = r0; r < D3R; r += 4) {
    float lo = 0.f, hi = 0.f;
#pragma unroll
    for (int t = 0; t < 8; ++t) {
      const float v = sA2[(2 * r + t) * NCH + c];
      lo = fmaf(v, F_LO[t], lo);
      hi = fmaf(v, F_HI[t], hi);
    }
    sD3[r * NCH + c] = hi;
    sA3[r * NCH + c] = lo;
  }
  __syncthreads();

  // ---- Stage 4: upsampled writes for out rows [4i0, 4i0+64).
  for (int r = r0; r < 4 * T3; r += 4) {
    const int j = jlo + r;
    float* orow = outb + (size_t)j * 256;
    {
      const int m = j >> 1;
      int mo = (j & 1) ? m + 1 : m - 1;
      mo = min(max(mo, 0), L2 - 1);
      orow[NCH + c] = 0.75f * sD2[(m - a2base) * NCH + c] +
                      0.25f * sD2[(mo - a2base) * NCH + c];
    }
    {
      const int m = j >> 2;
      const int p = j & 3;
      const float wo = (p == 0 || p == 3) ? 0.375f : 0.125f;
      const float wc = 1.0f - wo;
      int mo = (p < 2) ? m - 1 : m + 1;
      mo = min(max(mo, 0), L3 - 1);
      const int ml = (m - (i0 - 1)) * NCH + c;
      const int mol = (mo - (i0 - 1)) * NCH + c;
      orow[2 * NCH + c] = wc * sD3[ml] + wo * sD3[mol];
      orow[3 * NCH + c] = wc * sA3[ml] + wo * sA3[mol];
    }
  }
}

extern "C" void kernel_launch(void* const* d_in, const int* in_sizes, int n_in,
                              void* d_out, int out_size, void* d_ws, size_t ws_size,
                              hipStream_t stream) {
  const float* x = (const float*)d_in[0];
  float* out = (float*)d_out;
  k_fused<<<NB * (L3 / 16), 256, 0, stream>>>(x, out);
}

// Round 3
// 100.327 us; speedup vs baseline: 1.3993x; 1.3993x over previous
//
#include <hip/hip_runtime.h>

// FixedDb4DWT1D fully fused, float4-per-thread + register sliding windows.
// x: (32, 16384, 64) f32 -> out: (32, 8192, 256) f32
// out channel blocks: [D1 | up2(D2) | up4(D3) | up4(A3)]
//
// Block = 16 level-3 rows = 64 output rows. Thread = (row-subgroup, 4 channels).
// A1/A2/D2 in LDS (b128 access only); D3/A3 alias dead A1. x read straight
// from global as float4 with an 8-deep stride-2 register window.

#define NCH 64
#define NB 32
#define L0 16384
#define L1 8192
#define L2 4096
#define L3 2048
#define T3 16
#define STR 68   // LDS row stride in floats (pad: 68%32=4 banks shift per row)

__device__ constexpr float F_LO[8] = {
    -0.010597401784997278f, 0.032883011666982945f,
    0.030841381835986965f, -0.18703481171888114f,
    -0.02798376941698385f, 0.6308807679295904f,
    0.7148465705525415f,   0.23037781330885523f};
__device__ constexpr float F_HI[8] = {
    -0.23037781330885523f, 0.7148465705525415f,
    -0.6308807679295904f,  -0.02798376941698385f,
    0.18703481171888114f,  0.030841381835986965f,
    0.032883011666982945f, -0.010597401784997278f};

__device__ __forceinline__ void fma4(float4& a, float k, const float4& v) {
  a.x = fmaf(v.x, k, a.x); a.y = fmaf(v.y, k, a.y);
  a.z = fmaf(v.z, k, a.z); a.w = fmaf(v.w, k, a.w);
}

__global__ __launch_bounds__(256) void k_fused(const float* __restrict__ x,
                                               float* __restrict__ out) {
  constexpr int A1R = 4 * T3 + 26;  // 90 A1 rows, base 4*i0-13
  constexpr int A2R = 2 * T3 + 10;  // 42 A2/D2 rows, base 2*i0-5
  constexpr int D3R = T3 + 2;       // 18 D3/A3 rows, base i0-1
  __shared__ float smem[(A1R + 2 * A2R) * STR];   // 174*68*4 = 46.2 KB
  float* sA1 = smem;
  float* sA2 = smem + A1R * STR;
  float* sD2 = smem + (A1R + A2R) * STR;
  float* sD3 = smem;                // alias over sA1 rows 0..17 (dead)
  float* sA3 = smem + D3R * STR;    // alias over sA1 rows 18..35

  const int nt = L3 / T3;           // 128
  const int b = blockIdx.x / nt;
  const int i0 = (blockIdx.x % nt) * T3;
  const int sub = threadIdx.x >> 4;        // 0..15 row subgroup
  const int c4 = (threadIdx.x & 15) * 4;   // channel quad
  const float* xb = x + (size_t)b * L0 * NCH;
  float* outb = out + (size_t)b * L1 * 256;
  const int a1base = 4 * i0 - 13;

  // ---- Stage 1: A1 -> sA1 (LDS), D1 -> out block 0. x read direct global.
  {
    const int rs = sub * 6;                // subs 0..14 cover 90 rows
    if (rs < A1R) {
      if (i0 != 0 && i0 != (L3 - T3)) {    // interior: no bounds checks
        const float* xp = xb + (size_t)(8 * i0 - 29) * NCH + c4;  // local row 2r+t
        float4 w[8];
#pragma unroll
        for (int k = 0; k < 6; ++k)
          w[k] = *(const float4*)(xp + (size_t)(2 * rs + k) * NCH);
#pragma unroll
        for (int u = 0; u < 6; ++u) {
          const int r = rs + u;
          w[6] = *(const float4*)(xp + (size_t)(2 * r + 6) * NCH);
          w[7] = *(const float4*)(xp + (size_t)(2 * r + 7) * NCH);
          float4 lo = {0.f, 0.f, 0.f, 0.f}, hi = {0.f, 0.f, 0.f, 0.f};
#pragma unroll
          for (int t = 0; t < 8; ++t) { fma4(lo, F_LO[t], w[t]); fma4(hi, F_HI[t], w[t]); }
          *(float4*)&sA1[r * STR + c4] = lo;
          if (r >= 13 && r < 13 + 4 * T3)
            *(float4*)(outb + (size_t)(a1base + r) * 256 + c4) = hi;
#pragma unroll
          for (int k = 0; k < 6; ++k) w[k] = w[k + 2];
        }
      } else {                             // edge tiles: guarded taps
#pragma unroll
        for (int u = 0; u < 6; ++u) {
          const int r = rs + u;
          const int a = a1base + r;
          float4 lo = {0.f, 0.f, 0.f, 0.f}, hi = {0.f, 0.f, 0.f, 0.f};
          if (a >= 0 && a < L1) {
#pragma unroll
            for (int t = 0; t < 8; ++t) {
              const int g = 2 * a - 3 + t;
              float4 v = {0.f, 0.f, 0.f, 0.f};
              if (g >= 0 && g < L0) v = *(const float4*)(xb + (size_t)g * NCH + c4);
              fma4(lo, F_LO[t], v); fma4(hi, F_HI[t], v);
            }
          }
          *(float4*)&sA1[r * STR + c4] = lo;   // 0 outside [0,L1): level-2 pad
          if (r >= 13 && r < 13 + 4 * T3)
            *(float4*)(outb + (size_t)a * 256 + c4) = hi;
        }
      }
    }
  }
  __syncthreads();

  // ---- Stage 2: A2 -> sA2, D2 -> sD2 from sA1. Window over sA1.
  const int a2base = 2 * i0 - 5;
  if (sub < 14) {                          // 14 subs * 3 rows = 42
    const int rs = sub * 3;
    float4 v[8];
#pragma unroll
    for (int k = 0; k < 6; ++k) v[k] = *(float4*)&sA1[(2 * rs + k) * STR + c4];
#pragma unroll
    for (int u = 0; u < 3; ++u) {
      const int r = rs + u;
      v[6] = *(float4*)&sA1[(2 * r + 6) * STR + c4];
      v[7] = *(float4*)&sA1[(2 * r + 7) * STR + c4];
      float4 lo = {0.f, 0.f, 0.f, 0.f}, hi = {0.f, 0.f, 0.f, 0.f};
#pragma unroll
      for (int t = 0; t < 8; ++t) { fma4(lo, F_LO[t], v[t]); fma4(hi, F_HI[t], v[t]); }
      *(float4*)&sD2[r * STR + c4] = hi;
      const int a2 = a2base + r;
      const float4 z = {0.f, 0.f, 0.f, 0.f};
      *(float4*)&sA2[r * STR + c4] = (a2 >= 0 && a2 < L2) ? lo : z;  // level-3 pad
#pragma unroll
      for (int k = 0; k < 6; ++k) v[k] = v[k + 2];
    }
  }
  __syncthreads();

  // ---- Stage 3: D3 -> sD3, A3 -> sA3 from sA2 (writes alias dead sA1).
  if (sub < 9) {                           // 9 subs * 2 rows = 18
    const int rs = sub * 2;
    float4 v[8];
#pragma unroll
    for (int k = 0; k < 6; ++k) v[k] = *(float4*)&sA2[(2 * rs + k) * STR + c4];
#pragma unroll
    for (int u = 0; u < 2; ++u) {
      const int r = rs + u;
      v[6] = *(float4*)&sA2[(2 * r + 6) * STR + c4];
      v[7] = *(float4*)&sA2[(2 * r + 7) * STR + c4];
      float4 lo = {0.f, 0.f, 0.f, 0.f}, hi = {0.f, 0.f, 0.f, 0.f};
#pragma unroll
      for (int t = 0; t < 8; ++t) { fma4(lo, F_LO[t], v[t]); fma4(hi, F_HI[t], v[t]); }
      *(float4*)&sD3[r * STR + c4] = hi;
      *(float4*)&sA3[r * STR + c4] = lo;
#pragma unroll
      for (int k = 0; k < 6; ++k) v[k] = v[k + 2];
    }
  }
  __syncthreads();

  // ---- Stage 4: upsample bands 1..3 for out rows [4i0, 4i0+64), float4 stores.
  {
    const int jl0 = threadIdx.x >> 4;      // 16 rows per pass, 4 passes
#pragma unroll
    for (int it = 0; it < 4; ++it) {
      const int jl = jl0 + it * 16;
      const int j = 4 * i0 + jl;
      float* orow = outb + (size_t)j * 256;
      {  // band 1: up2(D2)
        const int m = j >> 1;
        int mo = (j & 1) ? m + 1 : m - 1;
        mo = min(max(mo, 0), L2 - 1);
        const float4 a = *(float4*)&sD2[(m - a2base) * STR + c4];
        const float4 o = *(float4*)&sD2[(mo - a2base) * STR + c4];
        float4 vv;
        vv.x = fmaf(0.75f, a.x, 0.25f * o.x); vv.y = fmaf(0.75f, a.y, 0.25f * o.y);
        vv.z = fmaf(0.75f, a.z, 0.25f * o.z); vv.w = fmaf(0.75f, a.w, 0.25f * o.w);
        *(float4*)(orow + NCH + c4) = vv;
      }
      {  // bands 2,3: up4(D3), up4(A3)
        const int m = j >> 2;
        const int p = j & 3;
        const float wo = (p == 0 || p == 3) ? 0.375f : 0.125f;
        const float wc = 1.0f - wo;
        int mo = (p < 2) ? m - 1 : m + 1;
        mo = min(max(mo, 0), L3 - 1);
        const int ml = (m - (i0 - 1)) * STR + c4;
        const int mol = (mo - (i0 - 1)) * STR + c4;
        const float4 d = *(float4*)&sD3[ml];
        const float4 dn = *(float4*)&sD3[mol];
        const float4 a = *(float4*)&sA3[ml];
        const float4 an = *(float4*)&sA3[mol];
        float4 v2, v3;
        v2.x = fmaf(wc, d.x, wo * dn.x); v2.y = fmaf(wc, d.y, wo * dn.y);
        v2.z = fmaf(wc, d.z, wo * dn.z); v2.w = fmaf(wc, d.w, wo * dn.w);
        v3.x = fmaf(wc, a.x, wo * an.x); v3.y = fmaf(wc, a.y, wo * an.y);
        v3.z = fmaf(wc, a.z, wo * an.z); v3.w = fmaf(wc, a.w, wo * an.w);
        *(float4*)(orow + 2 * NCH + c4) = v2;
        *(float4*)(orow + 3 * NCH + c4) = v3;
      }
    }
  }
}

extern "C" void kernel_launch(void* const* d_in, const int* in_sizes, int n_in,
                              void* d_out, int out_size, void* d_ws, size_t ws_size,
                              hipStream_t stream) {
  const float* x = (const float*)d_in[0];
  float* out = (float*)d_out;
  k_fused<<<NB * (L3 / T3), 256, 0, stream>>>(x, out);
}

// Round 4
// 70.077 us; speedup vs baseline: 2.0034x; 1.4317x over previous
//
#include <hip/hip_runtime.h>

// FixedDb4DWT1D fully fused, float4-per-thread + register windows.
// x: (32, 16384, 64) f32 -> out: (32, 8192, 256) f32
// out channel blocks: [D1 | up2(D2) | up4(D3) | up4(A3)]
//
// Block = 16 level-3 rows = 64 output rows. Thread = (row-subgroup, 4 channels).
// A1/A2/D2 in LDS (b128 only); D3/A3 alias dead A1. x read direct from global
// (18 hoisted float4 loads / thread). XCD-swizzled blocks; NT out stores.

#define NCH 64
#define NB 32
#define L0 16384
#define L1 8192
#define L2 4096
#define L3 2048
#define T3 16
#define STR 68

typedef float f32x4 __attribute__((ext_vector_type(4)));

__device__ constexpr float F_LO[8] = {
    -0.010597401784997278f, 0.032883011666982945f,
    0.030841381835986965f, -0.18703481171888114f,
    -0.02798376941698385f, 0.6308807679295904f,
    0.7148465705525415f,   0.23037781330885523f};
__device__ constexpr float F_HI[8] = {
    -0.23037781330885523f, 0.7148465705525415f,
    -0.6308807679295904f,  -0.02798376941698385f,
    0.18703481171888114f,  0.030841381835986965f,
    0.032883011666982945f, -0.010597401784997278f};

__device__ __forceinline__ void fma4(float4& a, float k, const float4& v) {
  a.x = fmaf(v.x, k, a.x); a.y = fmaf(v.y, k, a.y);
  a.z = fmaf(v.z, k, a.z); a.w = fmaf(v.w, k, a.w);
}
__device__ __forceinline__ void st_nt(float* p, const float4 v) {
  f32x4 t = {v.x, v.y, v.z, v.w};
  __builtin_nontemporal_store(t, (f32x4*)p);
}

__global__ __launch_bounds__(256) void k_fused(const float* __restrict__ x,
                                               float* __restrict__ out) {
  constexpr int A1R = 4 * T3 + 26;  // 90 A1 rows, base 4*i0-13
  constexpr int A2R = 2 * T3 + 10;  // 42 A2/D2 rows, base 2*i0-5
  constexpr int D3R = T3 + 2;       // 18 D3/A3 rows, base i0-1
  __shared__ float smem[(A1R + 2 * A2R) * STR];   // 174*272B = 46.2 KB
  float* sA1 = smem;
  float* sA2 = smem + A1R * STR;
  float* sD2 = smem + (A1R + A2R) * STR;
  float* sD3 = smem;                // alias over dead sA1 rows
  float* sA3 = smem + D3R * STR;

  // XCD-aware swizzle: 4096 blocks, 8 XCDs, 512/XCD contiguous chunk.
  const int bid = blockIdx.x;
  const int swz = (bid & 7) * 512 + (bid >> 3);
  const int nt = L3 / T3;           // 128
  const int b = swz / nt;
  const int i0 = (swz % nt) * T3;
  const int sub = threadIdx.x >> 4;        // 0..15 row subgroup
  const int c4 = (threadIdx.x & 15) * 4;   // channel quad
  const float* xb = x + (size_t)b * L0 * NCH;
  float* outb = out + (size_t)b * L1 * 256;
  const int a1base = 4 * i0 - 13;

  // ---- Stage 1: A1 -> sA1, D1 -> out block 0. 18 independent loads/thread.
  {
    const int rs = sub * 6;                // subs 0..14 cover 90 rows
    if (rs < A1R) {
      if (i0 != 0 && i0 != (L3 - T3)) {    // interior: unguarded
        const float* xp = xb + (size_t)(8 * i0 - 29 + 2 * rs) * NCH + c4;
        float4 w[18];
#pragma unroll
        for (int k = 0; k < 18; ++k)
          w[k] = *(const float4*)(xp + (size_t)k * NCH);
#pragma unroll
        for (int u = 0; u < 6; ++u) {
          const int r = rs + u;
          float4 lo = {0.f, 0.f, 0.f, 0.f}, hi = {0.f, 0.f, 0.f, 0.f};
#pragma unroll
          for (int t = 0; t < 8; ++t) {
            fma4(lo, F_LO[t], w[2 * u + t]); fma4(hi, F_HI[t], w[2 * u + t]);
          }
          *(float4*)&sA1[r * STR + c4] = lo;
          if (r >= 13 && r < 13 + 4 * T3)
            st_nt(outb + (size_t)(a1base + r) * 256 + c4, hi);
        }
      } else {                             // edge tiles: guarded taps
#pragma unroll
        for (int u = 0; u < 6; ++u) {
          const int r = rs + u;
          const int a = a1base + r;
          float4 lo = {0.f, 0.f, 0.f, 0.f}, hi = {0.f, 0.f, 0.f, 0.f};
          if (a >= 0 && a < L1) {
#pragma unroll
            for (int t = 0; t < 8; ++t) {
              const int g = 2 * a - 3 + t;
              float4 v = {0.f, 0.f, 0.f, 0.f};
              if (g >= 0 && g < L0) v = *(const float4*)(xb + (size_t)g * NCH + c4);
              fma4(lo, F_LO[t], v); fma4(hi, F_HI[t], v);
            }
          }
          *(float4*)&sA1[r * STR + c4] = lo;   // 0 outside [0,L1): level-2 pad
          if (r >= 13 && r < 13 + 4 * T3)
            st_nt(outb + (size_t)a * 256 + c4, hi);
        }
      }
    }
  }
  __syncthreads();

  // ---- Stage 2: A2 -> sA2, D2 -> sD2 from sA1 (register window).
  const int a2base = 2 * i0 - 5;
  if (sub < 14) {                          // 14 subs * 3 rows = 42
    const int rs = sub * 3;
    float4 v[8];
#pragma unroll
    for (int k = 0; k < 6; ++k) v[k] = *(float4*)&sA1[(2 * rs + k) * STR + c4];
#pragma unroll
    for (int u = 0; u < 3; ++u) {
      const int r = rs + u;
      v[6] = *(float4*)&sA1[(2 * r + 6) * STR + c4];
      v[7] = *(float4*)&sA1[(2 * r + 7) * STR + c4];
      float4 lo = {0.f, 0.f, 0.f, 0.f}, hi = {0.f, 0.f, 0.f, 0.f};
#pragma unroll
      for (int t = 0; t < 8; ++t) { fma4(lo, F_LO[t], v[t]); fma4(hi, F_HI[t], v[t]); }
      *(float4*)&sD2[r * STR + c4] = hi;
      const int a2 = a2base + r;
      const float4 z = {0.f, 0.f, 0.f, 0.f};
      *(float4*)&sA2[r * STR + c4] = (a2 >= 0 && a2 < L2) ? lo : z;  // level-3 pad
#pragma unroll
      for (int k = 0; k < 6; ++k) v[k] = v[k + 2];
    }
  }
  __syncthreads();

  // ---- Stage 3: D3 -> sD3, A3 -> sA3 from sA2 (writes alias dead sA1).
  if (sub < 9) {                           // 9 subs * 2 rows = 18
    const int rs = sub * 2;
    float4 v[8];
#pragma unroll
    for (int k = 0; k < 6; ++k) v[k] = *(float4*)&sA2[(2 * rs + k) * STR + c4];
#pragma unroll
    for (int u = 0; u < 2; ++u) {
      const int r = rs + u;
      v[6] = *(float4*)&sA2[(2 * r + 6) * STR + c4];
      v[7] = *(float4*)&sA2[(2 * r + 7) * STR + c4];
      float4 lo = {0.f, 0.f, 0.f, 0.f}, hi = {0.f, 0.f, 0.f, 0.f};
#pragma unroll
      for (int t = 0; t < 8; ++t) { fma4(lo, F_LO[t], v[t]); fma4(hi, F_HI[t], v[t]); }
      *(float4*)&sD3[r * STR + c4] = hi;
      *(float4*)&sA3[r * STR + c4] = lo;
#pragma unroll
      for (int k = 0; k < 6; ++k) v[k] = v[k + 2];
    }
  }
  __syncthreads();

  // ---- Stage 4: upsample bands 1..3 for out rows [4i0, 4i0+64).
  {
    const int jl0 = threadIdx.x >> 4;
#pragma unroll
    for (int it = 0; it < 4; ++it) {
      const int j = 4 * i0 + jl0 + it * 16;
      float* orow = outb + (size_t)j * 256;
      {  // band 1: up2(D2)
        const int m = j >> 1;
        int mo = (j & 1) ? m + 1 : m - 1;
        mo = min(max(mo, 0), L2 - 1);
        const float4 a = *(float4*)&sD2[(m - a2base) * STR + c4];
        const float4 o = *(float4*)&sD2[(mo - a2base) * STR + c4];
        float4 vv;
        vv.x = fmaf(0.75f, a.x, 0.25f * o.x); vv.y = fmaf(0.75f, a.y, 0.25f * o.y);
        vv.z = fmaf(0.75f, a.z, 0.25f * o.z); vv.w = fmaf(0.75f, a.w, 0.25f * o.w);
        st_nt(orow + NCH + c4, vv);
      }
      {  // bands 2,3: up4(D3), up4(A3)
        const int m = j >> 2;
        const int p = j & 3;
        const float wo = (p == 0 || p == 3) ? 0.375f : 0.125f;
        const float wc = 1.0f - wo;
        int mo = (p < 2) ? m - 1 : m + 1;
        mo = min(max(mo, 0), L3 - 1);
        const int ml = (m - (i0 - 1)) * STR + c4;
        const int mol = (mo - (i0 - 1)) * STR + c4;
        const float4 d = *(float4*)&sD3[ml];
        const float4 dn = *(float4*)&sD3[mol];
        const float4 a = *(float4*)&sA3[ml];
        const float4 an = *(float4*)&sA3[mol];
        float4 v2, v3;
        v2.x = fmaf(wc, d.x, wo * dn.x); v2.y = fmaf(wc, d.y, wo * dn.y);
        v2.z = fmaf(wc, d.z, wo * dn.z); v2.w = fmaf(wc, d.w, wo * dn.w);
        v3.x = fmaf(wc, a.x, wo * an.x); v3.y = fmaf(wc, a.y, wo * an.y);
        v3.z = fmaf(wc, a.z, wo * an.z); v3.w = fmaf(wc, a.w, wo * an.w);
        st_nt(orow + 2 * NCH + c4, v2);
        st_nt(orow + 3 * NCH + c4, v3);
      }
    }
  }
}

extern "C" void kernel_launch(void* const* d_in, const int* in_sizes, int n_in,
                              void* d_out, int out_size, void* d_ws, size_t ws_size,
                              hipStream_t stream) {
  const float* x = (const float*)d_in[0];
  float* out = (float*)d_out;
  k_fused<<<NB * (L3 / T3), 256, 0, stream>>>(x, out);
}

// Round 5
// 69.780 us; speedup vs baseline: 2.0119x; 1.0043x over previous
//
#include <hip/hip_runtime.h>

// FixedDb4DWT1D fully fused, float4-per-thread + register windows.
// x: (32, 16384, 64) f32 -> out: (32, 8192, 256) f32
// out channel blocks: [D1 | up2(D2) | up4(D3) | up4(A3)]
//
// Block = 16 level-3 rows = 64 output rows. Thread = (row-subgroup, 4 channels).
// A1/A2/D2 in LDS (b128 only); D3/A3 alias dead A1. x read direct from global
// (18 hoisted float4 loads / thread). XCD-swizzled blocks; NT out stores.
// ALL global stores deferred to stage 4 so no mid-kernel barrier drains them.

#define NCH 64
#define NB 32
#define L0 16384
#define L1 8192
#define L2 4096
#define L3 2048
#define T3 16
#define STR 68

typedef float f32x4 __attribute__((ext_vector_type(4)));

__device__ constexpr float F_LO[8] = {
    -0.010597401784997278f, 0.032883011666982945f,
    0.030841381835986965f, -0.18703481171888114f,
    -0.02798376941698385f, 0.6308807679295904f,
    0.7148465705525415f,   0.23037781330885523f};
__device__ constexpr float F_HI[8] = {
    -0.23037781330885523f, 0.7148465705525415f,
    -0.6308807679295904f,  -0.02798376941698385f,
    0.18703481171888114f,  0.030841381835986965f,
    0.032883011666982945f, -0.010597401784997278f};

__device__ __forceinline__ void fma4(float4& a, float k, const float4& v) {
  a.x = fmaf(v.x, k, a.x); a.y = fmaf(v.y, k, a.y);
  a.z = fmaf(v.z, k, a.z); a.w = fmaf(v.w, k, a.w);
}
__device__ __forceinline__ void st_nt(float* p, const float4 v) {
  f32x4 t = {v.x, v.y, v.z, v.w};
  __builtin_nontemporal_store(t, (f32x4*)p);
}

__global__ __launch_bounds__(256) void k_fused(const float* __restrict__ x,
                                               float* __restrict__ out) {
  constexpr int A1R = 4 * T3 + 26;  // 90 A1 rows, base 4*i0-13
  constexpr int A2R = 2 * T3 + 10;  // 42 A2/D2 rows, base 2*i0-5
  constexpr int D3R = T3 + 2;       // 18 D3/A3 rows, base i0-1
  __shared__ float smem[(A1R + 2 * A2R) * STR];   // 174*272B = 46.2 KB
  float* sA1 = smem;
  float* sA2 = smem + A1R * STR;
  float* sD2 = smem + (A1R + A2R) * STR;
  float* sD3 = smem;                // alias over dead sA1 rows
  float* sA3 = smem + D3R * STR;

  // XCD-aware swizzle: 4096 blocks, 8 XCDs, 512/XCD contiguous chunk.
  const int bid = blockIdx.x;
  const int swz = (bid & 7) * 512 + (bid >> 3);
  const int nt = L3 / T3;           // 128
  const int b = swz / nt;
  const int i0 = (swz % nt) * T3;
  const int sub = threadIdx.x >> 4;        // 0..15 row subgroup
  const int c4 = (threadIdx.x & 15) * 4;   // channel quad
  const float* xb = x + (size_t)b * L0 * NCH;
  float* outb = out + (size_t)b * L1 * 256;
  const int a1base = 4 * i0 - 13;
  const int rs1 = sub * 6;                 // this thread's stage-1 row base

  float4 hiv[6];                           // D1 values, stored in stage 4
#pragma unroll
  for (int u = 0; u < 6; ++u) hiv[u] = make_float4(0.f, 0.f, 0.f, 0.f);

  // ---- Stage 1: A1 -> sA1 (LDS only; no global stores before the barrier).
  if (rs1 < A1R) {                         // subs 0..14 cover 90 rows
    if (i0 != 0 && i0 != (L3 - T3)) {      // interior: unguarded
      const float* xp = xb + (size_t)(8 * i0 - 29 + 2 * rs1) * NCH + c4;
      float4 w[18];
#pragma unroll
      for (int k = 0; k < 18; ++k)
        w[k] = *(const float4*)(xp + (size_t)k * NCH);
#pragma unroll
      for (int u = 0; u < 6; ++u) {
        float4 lo = {0.f, 0.f, 0.f, 0.f}, hi = {0.f, 0.f, 0.f, 0.f};
#pragma unroll
        for (int t = 0; t < 8; ++t) {
          fma4(lo, F_LO[t], w[2 * u + t]); fma4(hi, F_HI[t], w[2 * u + t]);
        }
        *(float4*)&sA1[(rs1 + u) * STR + c4] = lo;
        hiv[u] = hi;
      }
    } else {                               // edge tiles: guarded taps
#pragma unroll
      for (int u = 0; u < 6; ++u) {
        const int a = a1base + rs1 + u;
        float4 lo = {0.f, 0.f, 0.f, 0.f}, hi = {0.f, 0.f, 0.f, 0.f};
        if (a >= 0 && a < L1) {
#pragma unroll
          for (int t = 0; t < 8; ++t) {
            const int g = 2 * a - 3 + t;
            float4 v = {0.f, 0.f, 0.f, 0.f};
            if (g >= 0 && g < L0) v = *(const float4*)(xb + (size_t)g * NCH + c4);
            fma4(lo, F_LO[t], v); fma4(hi, F_HI[t], v);
          }
        }
        *(float4*)&sA1[(rs1 + u) * STR + c4] = lo;  // 0 outside [0,L1)
        hiv[u] = hi;
      }
    }
  }
  __syncthreads();

  // ---- Stage 2: A2 -> sA2, D2 -> sD2 from sA1 (register window).
  const int a2base = 2 * i0 - 5;
  if (sub < 14) {                          // 14 subs * 3 rows = 42
    const int rs = sub * 3;
    float4 v[8];
#pragma unroll
    for (int k = 0; k < 6; ++k) v[k] = *(float4*)&sA1[(2 * rs + k) * STR + c4];
#pragma unroll
    for (int u = 0; u < 3; ++u) {
      const int r = rs + u;
      v[6] = *(float4*)&sA1[(2 * r + 6) * STR + c4];
      v[7] = *(float4*)&sA1[(2 * r + 7) * STR + c4];
      float4 lo = {0.f, 0.f, 0.f, 0.f}, hi = {0.f, 0.f, 0.f, 0.f};
#pragma unroll
      for (int t = 0; t < 8; ++t) { fma4(lo, F_LO[t], v[t]); fma4(hi, F_HI[t], v[t]); }
      *(float4*)&sD2[r * STR + c4] = hi;
      const int a2 = a2base + r;
      const float4 z = {0.f, 0.f, 0.f, 0.f};
      *(float4*)&sA2[r * STR + c4] = (a2 >= 0 && a2 < L2) ? lo : z;  // level-3 pad
#pragma unroll
      for (int k = 0; k < 6; ++k) v[k] = v[k + 2];
    }
  }
  __syncthreads();

  // ---- Stage 3: D3 -> sD3, A3 -> sA3 from sA2 (writes alias dead sA1).
  if (sub < 9) {                           // 9 subs * 2 rows = 18
    const int rs = sub * 2;
    float4 v[8];
#pragma unroll
    for (int k = 0; k < 6; ++k) v[k] = *(float4*)&sA2[(2 * rs + k) * STR + c4];
#pragma unroll
    for (int u = 0; u < 2; ++u) {
      const int r = rs + u;
      v[6] = *(float4*)&sA2[(2 * r + 6) * STR + c4];
      v[7] = *(float4*)&sA2[(2 * r + 7) * STR + c4];
      float4 lo = {0.f, 0.f, 0.f, 0.f}, hi = {0.f, 0.f, 0.f, 0.f};
#pragma unroll
      for (int t = 0; t < 8; ++t) { fma4(lo, F_LO[t], v[t]); fma4(hi, F_HI[t], v[t]); }
      *(float4*)&sD3[r * STR + c4] = hi;
      *(float4*)&sA3[r * STR + c4] = lo;
#pragma unroll
      for (int k = 0; k < 6; ++k) v[k] = v[k + 2];
    }
  }
  __syncthreads();

  // ---- Stage 4: ALL global stores. D1 from hiv regs; bands 1..3 from LDS.
  if (rs1 < A1R) {
#pragma unroll
    for (int u = 0; u < 6; ++u) {
      const int r = rs1 + u;
      if (r >= 13 && r < 13 + 4 * T3)
        st_nt(outb + (size_t)(a1base + r) * 256 + c4, hiv[u]);
    }
  }
  {
    const int jl0 = threadIdx.x >> 4;
#pragma unroll
    for (int it = 0; it < 4; ++it) {
      const int j = 4 * i0 + jl0 + it * 16;
      float* orow = outb + (size_t)j * 256;
      {  // band 1: up2(D2)
        const int m = j >> 1;
        int mo = (j & 1) ? m + 1 : m - 1;
        mo = min(max(mo, 0), L2 - 1);
        const float4 a = *(float4*)&sD2[(m - a2base) * STR + c4];
        const float4 o = *(float4*)&sD2[(mo - a2base) * STR + c4];
        float4 vv;
        vv.x = fmaf(0.75f, a.x, 0.25f * o.x); vv.y = fmaf(0.75f, a.y, 0.25f * o.y);
        vv.z = fmaf(0.75f, a.z, 0.25f * o.z); vv.w = fmaf(0.75f, a.w, 0.25f * o.w);
        st_nt(orow + NCH + c4, vv);
      }
      {  // bands 2,3: up4(D3), up4(A3)
        const int m = j >> 2;
        const int p = j & 3;
        const float wo = (p == 0 || p == 3) ? 0.375f : 0.125f;
        const float wc = 1.0f - wo;
        int mo = (p < 2) ? m - 1 : m + 1;
        mo = min(max(mo, 0), L3 - 1);
        const int ml = (m - (i0 - 1)) * STR + c4;
        const int mol = (mo - (i0 - 1)) * STR + c4;
        const float4 d = *(float4*)&sD3[ml];
        const float4 dn = *(float4*)&sD3[mol];
        const float4 a = *(float4*)&sA3[ml];
        const float4 an = *(float4*)&sA3[mol];
        float4 v2, v3;
        v2.x = fmaf(wc, d.x, wo * dn.x); v2.y = fmaf(wc, d.y, wo * dn.y);
        v2.z = fmaf(wc, d.z, wo * dn.z); v2.w = fmaf(wc, d.w, wo * dn.w);
        v3.x = fmaf(wc, a.x, wo * an.x); v3.y = fmaf(wc, a.y, wo * an.y);
        v3.z = fmaf(wc, a.z, wo * an.z); v3.w = fmaf(wc, a.w, wo * an.w);
        st_nt(orow + 2 * NCH + c4, v2);
        st_nt(orow + 3 * NCH + c4, v3);
      }
    }
  }
}

extern "C" void kernel_launch(void* const* d_in, const int* in_sizes, int n_in,
                              void* d_out, int out_size, void* d_ws, size_t ws_size,
                              hipStream_t stream) {
  const float* x = (const float*)d_in[0];
  float* out = (float*)d_out;
  k_fused<<<NB * (L3 / T3), 256, 0, stream>>>(x, out);
}